// Round 3
// baseline (477.389 us; speedup 1.0000x reference)
//
#include <hip/hip_runtime.h>

typedef unsigned short u16;
typedef __attribute__((ext_vector_type(8))) short bf16x8;
typedef __attribute__((ext_vector_type(4))) float f32x4;

__device__ __forceinline__ u16 f2bf(float f) {
  union { float f; unsigned u; } v; v.f = f;
  unsigned r = v.u + 0x7FFFu + ((v.u >> 16) & 1u);
  return (u16)(r >> 16);
}
__device__ __forceinline__ float bf2f(u16 h) {
  union { unsigned u; float f; } v; v.u = ((unsigned)h) << 16; return v.f;
}
__device__ __forceinline__ unsigned pk2(float a, float b) {
  return (unsigned)f2bf(a) | ((unsigned)f2bf(b) << 16);
}
// hardware packed cvt: lo=bf16(a), hi=bf16(b)
__device__ __forceinline__ unsigned cvtpk(float a, float b) {
  unsigned r;
  asm("v_cvt_pk_bf16_f32 %0, %1, %2" : "=v"(r) : "v"(a), "v"(b));
  return r;
}
__device__ __forceinline__ void gld16(const void* g, void* l) {
  __builtin_amdgcn_global_load_lds(
      (const __attribute__((address_space(1))) unsigned int*)g,
      (__attribute__((address_space(3))) unsigned int*)l, 16, 0, 0);
}

// transpose + convert: in [R][C] f32 -> out [Cout][R] bf16 (rows c>=C are zero)
__global__ __launch_bounds__(256)
void tr_cvt_k(const float* __restrict__ in, u16* __restrict__ out,
              int R, int C, int Cout) {
  __shared__ float tile[32][33];
  int tj = blockIdx.x * 32, ti = blockIdx.y * 32;
  int t = threadIdx.x, c = t & 31, r0 = t >> 5;
#pragma unroll
  for (int p = 0; p < 4; ++p) {
    int r = r0 + p * 8;
    tile[r][c] = (tj + c < C) ? in[(size_t)(ti + r) * C + (tj + c)] : 0.f;
  }
  __syncthreads();
#pragma unroll
  for (int p = 0; p < 4; ++p) {
    int rr = r0 + p * 8;
    out[(size_t)(tj + rr) * R + (ti + c)] = f2bf(tile[c][rr]);
  }
}

// row-major f32 -> bf16 convert
__global__ __launch_bounds__(256)
void cvt_rm_k(const float* __restrict__ in, u16* __restrict__ out, int n8) {
  int idx = blockIdx.x * 256 + threadIdx.x;
  if (idx >= n8) return;
  float4 f0 = ((const float4*)in)[idx * 2];
  float4 f1 = ((const float4*)in)[idx * 2 + 1];
  uint4 q;
  q.x = pk2(f0.x, f0.y); q.y = pk2(f0.z, f0.w);
  q.z = pk2(f1.x, f1.y); q.w = pk2(f1.z, f1.w);
  ((uint4*)out)[idx] = q;
}

// d[i] = float(bf16_cvtpk(adj[i][i]))  (same rounding as GEMM A staging)
__global__ __launch_bounds__(256)
void diag_k(const float* __restrict__ adj, float* __restrict__ d) {
  int i = blockIdx.x * 256 + threadIdx.x;
  unsigned u = cvtpk(adj[(size_t)i * 8193], 0.f);
  union { unsigned u; float f; } v; v.u = u << 16;
  d[i] = v.f;
}

// Big GEMM: part[kp][8192][BN] = A[8192,8192] @ Bt[BN,8192]^T  (k-panel kp)
// BN=256: BM=64, split-K=2.  BN=64: BM=128, split-K=4.  8 waves, dbuf gld_lds.
// AKIND: 0 = A fp32, 1 = A fp32 + store bf16 copy to Aout, 2 = A bf16.
template <int BN, int AKIND>
__global__ __launch_bounds__(512)
void bgemm_k(const void* __restrict__ Av, const u16* __restrict__ Bt,
             float* __restrict__ part, u16* __restrict__ Aout) {
  constexpr int BM = (BN == 256) ? 64 : 128;
  constexpr int SPLITK = (BN == 256) ? 2 : 4;
  constexpr int MTILES = 8192 / BM;
  constexpr int KP = 8192 / SPLITK;
  constexpr int TT = KP / 64;
  constexpr bool ABF = (AKIND == 2);
  constexpr int AROWB = ABF ? 128 : 256;  // LDS bytes per A row (64 k)
  constexpr int ATILE = BM * AROWB;
  constexpr int NA = ATILE / 8192;  // A stage issues per wave
  constexpr int NB = BN * 128 / 8192;

  __shared__ char sA[2][ATILE];
  __shared__ u16 sB[2][BN * 64];
  const int t = threadIdx.x, lane = t & 63, w = t >> 6;
  const int s = ((blockIdx.x & 7) << 5) | (blockIdx.x >> 3);  // XCD swizzle
  const int kp = s / MTILES, m = s % MTILES;
  const size_t mBase = (size_t)m * BM;
  const int k0base = kp * KP;

  constexpr int FR = 2;
  constexpr int FC = (BN == 256) ? 4 : 2;
  const int waveM = (BN == 256) ? ((w >> 2) * 32) : ((w >> 1) * 32);
  const int waveN = (BN == 256) ? ((w & 3) * 64) : ((w & 1) * 32);

  f32x4 acc[FR][FC];
#pragma unroll
  for (int a = 0; a < FR; ++a)
#pragma unroll
    for (int b = 0; b < FC; ++b) acc[a][b] = (f32x4){0.f, 0.f, 0.f, 0.f};

  auto stage = [&](int buf, int tt) {
    const int k0 = k0base + tt * 64;
#pragma unroll
    for (int i = 0; i < NA; ++i) {
      int lin = ((w * NA + i) << 10) + (lane << 4);
      int row = lin / AROWB;
      int kb = (lin & (AROWB - 1)) ^ ((row & 7) << 4);
      const char* g;
      if (ABF)
        g = (const char*)Av + (((size_t)(mBase + row)) << 14) + ((size_t)k0 << 1) + kb;
      else
        g = (const char*)Av + (((size_t)(mBase + row)) << 15) + ((size_t)k0 << 2) + kb;
      gld16(g, (char*)sA[buf] + ((w * NA + i) << 10));
    }
#pragma unroll
    for (int i = 0; i < NB; ++i) {
      int lin = ((w * NB + i) << 10) + (lane << 4);
      int n = lin >> 7;
      int kb = (lin & 127) ^ ((n & 7) << 4);
      const char* g = (const char*)Bt + ((size_t)n << 14) + ((size_t)k0 << 1) + kb;
      gld16(g, (char*)sB[buf] + ((w * NB + i) << 10));
    }
  };

  stage(0, 0);
  __syncthreads();
  for (int tt = 0; tt < TT; ++tt) {
    const int cur = tt & 1;
    if (tt < TT - 1) stage(cur ^ 1, tt + 1);
    const char* sa = (const char*)sA[cur];
    const char* sb = (const char*)sB[cur];
#pragma unroll
    for (int ks = 0; ks < 2; ++ks) {
      bf16x8 av[FR], bv[FC];
#pragma unroll
      for (int fr = 0; fr < FR; ++fr) {
        int row = waveM + fr * 16 + (lane & 15);
        if (ABF) {
          int off = (row * 128 + ks * 64 + ((lane >> 4) * 16)) ^ ((row & 7) << 4);
          av[fr] = *(const bf16x8*)(sa + off);
        } else {
          int base = row * 256 + ks * 128 + ((lane >> 4) * 32);
          int sw = (row & 7) << 4;
          f32x4 x0 = *(const f32x4*)(sa + (base ^ sw));
          f32x4 x1 = *(const f32x4*)(sa + ((base + 16) ^ sw));
          union { bf16x8 v; unsigned u[4]; } pk;
          pk.u[0] = cvtpk(x0.x, x0.y); pk.u[1] = cvtpk(x0.z, x0.w);
          pk.u[2] = cvtpk(x1.x, x1.y); pk.u[3] = cvtpk(x1.z, x1.w);
          av[fr] = pk.v;
          if (AKIND == 1 && (w & 3) == 0) {
            int gk = k0base + tt * 64 + ks * 32 + ((lane >> 4) << 3);
            *(bf16x8*)(Aout + ((size_t)(mBase + row) << 13) + gk) = av[fr];
          }
        }
      }
#pragma unroll
      for (int fc = 0; fc < FC; ++fc) {
        int n = waveN + fc * 16 + (lane & 15);
        int off = (n * 128 + ks * 64 + ((lane >> 4) * 16)) ^ ((n & 7) << 4);
        bv[fc] = *(const bf16x8*)(sb + off);
      }
#pragma unroll
      for (int fr = 0; fr < FR; ++fr)
#pragma unroll
        for (int fc = 0; fc < FC; ++fc)
          acc[fr][fc] = __builtin_amdgcn_mfma_f32_16x16x32_bf16(
              av[fr], bv[fc], acc[fr][fc], 0, 0, 0);
    }
    __syncthreads();
  }

  float* pp = part + (size_t)kp * 8192 * BN + mBase * BN;
#pragma unroll
  for (int fr = 0; fr < FR; ++fr)
#pragma unroll
    for (int fc = 0; fc < FC; ++fc) {
      int col = waveN + fc * 16 + (lane & 15);
      int r0 = waveM + fr * 16 + ((lane >> 4) << 2);
#pragma unroll
      for (int j = 0; j < 4; ++j)
        pp[(size_t)(r0 + j) * BN + col] = acc[fr][fc][j];
    }
}

// Small GEMM: M=8192, K=256, A bf16 [8192][256] row-major, Bt [BN][256] bf16.
template <int BN, int EPI, bool TROUT>
__global__ __launch_bounds__(256)
void sgemm_k(const u16* __restrict__ Abf, const u16* __restrict__ Bt,
             float* __restrict__ C, int ldc, u16* __restrict__ Ct) {
  __shared__ u16 sA[32 * 256];
  __shared__ u16 sB[BN * 256];
  const int t = threadIdx.x, lane = t & 63, w = t >> 6;
  const int rowBase = blockIdx.x * 32;
  const u16* bt = Bt + (size_t)blockIdx.y * BN * 256;
  const int colBlk = blockIdx.y * BN;

#pragma unroll
  for (int i = 0; i < 4; ++i) {
    int lin = ((w * 4 + i) << 10) + (lane << 4);
    int row = lin >> 9;
    int kb = (lin & 511) ^ ((row & 7) << 4);
    const char* g = (const char*)Abf + ((size_t)(rowBase + row) << 9) + kb;
    gld16(g, (char*)sA + ((w * 4 + i) << 10));
  }
#pragma unroll
  for (int i = 0; i < BN / 8; ++i) {
    int lin = ((w * (BN / 8) + i) << 10) + (lane << 4);
    int n = lin >> 9;
    int kb = (lin & 511) ^ ((n & 7) << 4);
    const char* g = (const char*)bt + ((size_t)n << 9) + kb;
    gld16(g, (char*)sB + ((w * (BN / 8) + i) << 10));
  }
  __syncthreads();

  constexpr int FC = BN / 32;
  const int waveM = (w & 1) * 16;
  const int waveN = (w >> 1) * (BN / 2);
  f32x4 acc[FC];
#pragma unroll
  for (int b = 0; b < FC; ++b) acc[b] = (f32x4){0.f, 0.f, 0.f, 0.f};

#pragma unroll
  for (int ks = 0; ks < 8; ++ks) {
    int row = waveM + (lane & 15);
    int offA = (row * 512 + ks * 64 + ((lane >> 4) * 16)) ^ ((row & 7) << 4);
    bf16x8 av = *(const bf16x8*)((const char*)sA + offA);
#pragma unroll
    for (int fc = 0; fc < FC; ++fc) {
      int n = waveN + fc * 16 + (lane & 15);
      int offB = (n * 512 + ks * 64 + ((lane >> 4) * 16)) ^ ((n & 7) << 4);
      bf16x8 bv = *(const bf16x8*)((const char*)sB + offB);
      acc[fc] = __builtin_amdgcn_mfma_f32_16x16x32_bf16(av, bv, acc[fc], 0, 0, 0);
    }
  }

#pragma unroll
  for (int fc = 0; fc < FC; ++fc) {
    int col = waveN + fc * 16 + (lane & 15);
    int r0 = rowBase + waveM + ((lane >> 4) << 2);
    float o[4];
#pragma unroll
    for (int j = 0; j < 4; ++j) {
      float xv = acc[fc][j];
      if (EPI == 1) xv = fmaxf(xv, 0.f);
      if (EPI == 2) xv = (xv > 0.f) ? xv : 0.2f * xv;
      o[j] = xv;
    }
    if (TROUT) {
      uint2 q; q.x = pk2(o[0], o[1]); q.y = pk2(o[2], o[3]);
      *(uint2*)(Ct + (size_t)col * 8192 + r0) = q;
    } else {
      C[(size_t)(r0 + 0) * ldc + colBlk + col] = o[0];
      C[(size_t)(r0 + 1) * ldc + colBlk + col] = o[1];
      C[(size_t)(r0 + 2) * ldc + colBlk + col] = o[2];
      C[(size_t)(r0 + 3) * ldc + colBlk + col] = o[3];
    }
  }
}

// reduce 2 K-panel partials + epilogue. MODE 0: relu(+bias)->f32
// MODE 1: -d[i]*x -> bf16; MODE 2: relu(+bias)->bf16
template <int MODE>
__global__ __launch_bounds__(256)
void reduce_k(const float* __restrict__ part, const float* __restrict__ bias,
              const float* __restrict__ d, const u16* __restrict__ xbf,
              float* __restrict__ Cf, u16* __restrict__ Cb) {
  const int row = blockIdx.x, j = threadIdx.x;
  const size_t i = (size_t)row * 256 + j;
  const size_t S = (size_t)8192 * 256;
  float s = part[i] + part[i + S];
  if (MODE == 0) { s = fmaxf(s + bias[j], 0.f); Cf[i] = s; }
  if (MODE == 1) { s -= d[row] * bf2f(xbf[i]); Cb[i] = f2bf(s); }
  if (MODE == 2) { s = fmaxf(s + bias[j], 0.f); Cb[i] = f2bf(s); }
}

// reduce logits partials [4][8192][64] + b2, then log_softmax over 40 cols
__global__ __launch_bounds__(256)
void reduce_lsm_k(const float* __restrict__ part, const float* __restrict__ b2,
                  float* __restrict__ out) {
  const int t = threadIdx.x, lane = t & 63, w = t >> 6;
  const int row = blockIdx.x * 4 + w;
  const size_t i = (size_t)row * 64 + lane;
  const size_t S = (size_t)8192 * 64;
  float v = part[i] + part[i + S] + part[i + 2 * S] + part[i + 3 * S];
  v = (lane < 40) ? v + b2[lane] : -1e30f;
  float mx = v;
#pragma unroll
  for (int off = 32; off >= 1; off >>= 1) mx = fmaxf(mx, __shfl_xor(mx, off));
  float e = (lane < 40) ? expf(v - mx) : 0.f;
#pragma unroll
  for (int off = 32; off >= 1; off >>= 1) e += __shfl_xor(e, off);
  float ls = mx + logf(e);
  if (lane < 40) out[(size_t)row * 40 + lane] = v - ls;
}

// lp=(g+1)*base+b; L2-normalize row; xin_bf = bf16(0.5*(x+lp/nrm))
__global__ __launch_bounds__(256)
void fuse_k(const float* __restrict__ gb, const float* __restrict__ base,
            const float* __restrict__ x, u16* __restrict__ xin_bf) {
  const int row = blockIdx.x, t = threadIdx.x;
  const size_t i = (size_t)row * 256 + t;
  float g = gb[(size_t)row * 512 + t];
  float b = gb[(size_t)row * 512 + 256 + t];
  float lp = (g + 1.f) * base[i] + b;
  float s = lp * lp;
#pragma unroll
  for (int off = 32; off >= 1; off >>= 1) s += __shfl_xor(s, off);
  __shared__ float ws4[4];
  if ((t & 63) == 0) ws4[t >> 6] = s;
  __syncthreads();
  float nrm = fmaxf(sqrtf(ws4[0] + ws4[1] + ws4[2] + ws4[3]), 1e-12f);
  xin_bf[i] = f2bf(0.5f * (x[i] + lp / nrm));
}

extern "C" void kernel_launch(void* const* d_in, const int* in_sizes, int n_in,
                              void* d_out, int out_size, void* d_ws, size_t ws_size,
                              hipStream_t stream) {
  const float* x = (const float*)d_in[0];
  const float* adj_f = (const float*)d_in[1];
  const float* adj_a = (const float*)d_in[2];
  const float* Wp = (const float*)d_in[3];
  const float* bp = (const float*)d_in[4];
  const float* Wg = (const float*)d_in[5];
  const float* Wb = (const float*)d_in[6];
  const float* W1 = (const float*)d_in[7];
  const float* b1 = (const float*)d_in[8];
  const float* W2 = (const float*)d_in[9];
  const float* b2 = (const float*)d_in[10];
  float* out = (float*)d_out;

  char* ws = (char*)d_ws;
  size_t off = 0;
  auto alloc = [&](size_t bytes) {
    char* p = ws + off;
    off += (bytes + 255) & ~(size_t)255;
    return p;
  };
  float* part = (float*)alloc((size_t)2 * 8192 * 256 * 4);  // 16 MB (>= 4*8192*64*4)
  u16* featT = (u16*)alloc((size_t)256 * 8192 * 2);
  u16* featT64 = (u16*)alloc((size_t)64 * 8192 * 2);
  u16* xT = (u16*)alloc((size_t)256 * 8192 * 2);
  u16* xbf = (u16*)alloc((size_t)8192 * 256 * 2);
  u16* xin_bf = (u16*)alloc((size_t)8192 * 256 * 2);
  u16* neigh_bf = (u16*)alloc((size_t)8192 * 256 * 2);
  u16* h_bf = (u16*)alloc((size_t)8192 * 256 * 2);
  float* base = (float*)alloc((size_t)8192 * 256 * 4);
  float* gbuf = (float*)alloc((size_t)8192 * 512 * 4);
  u16* WpT = (u16*)alloc(256 * 256 * 2);
  u16* WgbT = (u16*)alloc(512 * 256 * 2);
  u16* W1T = (u16*)alloc(256 * 256 * 2);
  u16* W2T = (u16*)alloc(64 * 256 * 2);
  float* dd = (float*)alloc(8192 * 4);

  const size_t adjBytes = (size_t)8192 * 8192 * 2;
  bool useBf = (ws_size >= off + adjBytes + 256);
  u16* adj_bf = useBf ? (u16*)alloc(adjBytes) : nullptr;

  dim3 b256(256), b512(512);
  tr_cvt_k<<<dim3(8, 8), b256, 0, stream>>>(Wp, WpT, 256, 256, 256);
  tr_cvt_k<<<dim3(8, 8), b256, 0, stream>>>(Wg, WgbT, 256, 256, 256);
  tr_cvt_k<<<dim3(8, 8), b256, 0, stream>>>(Wb, WgbT + 256 * 256, 256, 256, 256);
  tr_cvt_k<<<dim3(8, 8), b256, 0, stream>>>(W1, W1T, 256, 256, 256);
  tr_cvt_k<<<dim3(2, 8), b256, 0, stream>>>(W2, W2T, 256, 40, 64);
  tr_cvt_k<<<dim3(8, 256), b256, 0, stream>>>(x, xT, 8192, 256, 256);
  cvt_rm_k<<<1024, b256, 0, stream>>>(x, xbf, 8192 * 256 / 8);
  diag_k<<<32, b256, 0, stream>>>(adj_a, dd);

  // neighbor = adj_a @ x (diag removed in reduce); side-product: adj_a -> bf16
  if (useBf)
    bgemm_k<256, 1><<<256, b512, 0, stream>>>(adj_a, xT, part, adj_bf);
  else
    bgemm_k<256, 0><<<256, b512, 0, stream>>>(adj_a, xT, part, nullptr);
  reduce_k<1><<<8192, b256, 0, stream>>>(part, nullptr, dd, xbf, nullptr, neigh_bf);
  // gamma|beta = leaky(neigh @ [Wg|Wb])
  sgemm_k<256, 2, false><<<dim3(256, 2), b256, 0, stream>>>(neigh_bf, WgbT, gbuf, 512, nullptr);
  // t1^T = (x @ Wp)^T
  sgemm_k<256, 0, true><<<dim3(256, 1), b256, 0, stream>>>(xbf, WpT, nullptr, 0, featT);
  // base = relu(adj_f @ t1 + bp)
  bgemm_k<256, 0><<<256, b512, 0, stream>>>(adj_f, featT, part, nullptr);
  reduce_k<0><<<8192, b256, 0, stream>>>(part, bp, nullptr, nullptr, base, nullptr);
  // x_in
  fuse_k<<<8192, b256, 0, stream>>>(gbuf, base, x, xin_bf);
  // t2^T
  sgemm_k<256, 0, true><<<dim3(256, 1), b256, 0, stream>>>(xin_bf, W1T, nullptr, 0, featT);
  // h = relu(adj_a @ t2 + b1)
  if (useBf)
    bgemm_k<256, 2><<<256, b512, 0, stream>>>(adj_bf, featT, part, nullptr);
  else
    bgemm_k<256, 0><<<256, b512, 0, stream>>>(adj_a, featT, part, nullptr);
  reduce_k<2><<<8192, b256, 0, stream>>>(part, b1, nullptr, nullptr, nullptr, h_bf);
  // t3^T
  sgemm_k<64, 0, true><<<dim3(256, 1), b256, 0, stream>>>(h_bf, W2T, nullptr, 0, featT64);
  // logits partials + fused log_softmax
  if (useBf)
    bgemm_k<64, 2><<<256, b512, 0, stream>>>(adj_bf, featT64, part, nullptr);
  else
    bgemm_k<64, 0><<<256, b512, 0, stream>>>(adj_a, featT64, part, nullptr);
  reduce_lsm_k<<<2048, b256, 0, stream>>>(part, b2, out);
}